// Round 4
// baseline (431.627 us; speedup 1.0000x reference)
//
#include <hip/hip_runtime.h>
#include <cstdint>
#include <cstddef>

#define TT 4
#define BB 4
#define LL 1024
#define CC 256
#define HH 8
#define HD 32
#define NWIN 8
#define WIN 128
#define TOPKN 4
#define C3 768

// ---------------------------------------------------------------------------
// 1. region sums: region[b,n,c] = sum_t sum_r x[t,b,n*128+r,c]
__global__ __launch_bounds__(256) void region_kernel(const float* __restrict__ x,
                                                     float* __restrict__ region) {
    int bn = blockIdx.x;          // b*NWIN + n
    int b = bn >> 3, n = bn & 7;
    int c = threadIdx.x;
    float tot = 0.0f;
    for (int r = 0; r < WIN; ++r) {
        int l = n * WIN + r;
        float s = 0.0f;
        for (int t = 0; t < TT; ++t) {
            s += x[(((size_t)t * BB + b) * LL + l) * CC + c];
        }
        tot += s;
    }
    region[(size_t)bn * CC + c] = tot;
}

// ---------------------------------------------------------------------------
// 2. routing: attn_r[n,m] = dot(region[b,n], region[b,m]) * C^-0.5, top-4 per n
__global__ __launch_bounds__(64) void route_kernel(const float* __restrict__ region,
                                                   int* __restrict__ idx) {
    int b = blockIdx.x;
    __shared__ float reg[NWIN][CC];
    __shared__ float attn_r[NWIN][NWIN];
    int tid = threadIdx.x;
    for (int e = tid; e < NWIN * CC; e += 64)
        reg[e >> 8][e & 255] = region[(size_t)b * NWIN * CC + e];
    __syncthreads();
    int n = tid >> 3, m = tid & 7;
    float s = 0.0f;
    for (int c = 0; c < CC; ++c) s += reg[n][c] * reg[m][c];
    attn_r[n][m] = s * 0.0625f;   // C^-0.5 = 1/16 exact
    __syncthreads();
    if (tid < NWIN) {
        float vals[NWIN];
        for (int m2 = 0; m2 < NWIN; ++m2) vals[m2] = attn_r[tid][m2];
        for (int kk = 0; kk < TOPKN; ++kk) {
            int bi = 0; float bv = vals[0];
            for (int m2 = 1; m2 < NWIN; ++m2) {
                if (vals[m2] > bv) { bv = vals[m2]; bi = m2; }
            }
            idx[(b * NWIN + tid) * TOPKN + kk] = bi;
            vals[bi] = -INFINITY;
        }
    }
}

// ---------------------------------------------------------------------------
// 3. fp32 GEMM + bias (K ascending, exact)
__global__ __launch_bounds__(256) void gemm_bias(const float* __restrict__ A,
                                                 const float* __restrict__ W,
                                                 const float* __restrict__ bias,
                                                 float* __restrict__ C,
                                                 int M, int N, int K) {
    const int BM = 128, BN = 64, BK = 16, TM = 8, TN = 4;
    __shared__ float As[BK][BM + 4];
    __shared__ float Bs[BK][BN];
    int tid = threadIdx.x;
    int tx = tid & 15, ty = tid >> 4;
    int bm = blockIdx.x * BM, bn = blockIdx.y * BN;
    float acc[TM][TN] = {};
    for (int k0 = 0; k0 < K; k0 += BK) {
#pragma unroll
        for (int it = 0; it < 2; ++it) {
            int i = it * 256 + tid;
            int row = i >> 2, kc = (i & 3) * 4;
            float4 v = *(const float4*)(A + (size_t)(bm + row) * K + k0 + kc);
            As[kc + 0][row] = v.x; As[kc + 1][row] = v.y;
            As[kc + 2][row] = v.z; As[kc + 3][row] = v.w;
        }
        {
            int kr = tid >> 4, nc = (tid & 15) * 4;
            float4 v = *(const float4*)(W + (size_t)(k0 + kr) * N + bn + nc);
            *(float4*)&Bs[kr][nc] = v;
        }
        __syncthreads();
#pragma unroll
        for (int kk = 0; kk < BK; ++kk) {
            float a[TM], bb[TN];
            const float4* ap = (const float4*)&As[kk][ty * TM];
            float4 a0 = ap[0], a1 = ap[1];
            a[0]=a0.x; a[1]=a0.y; a[2]=a0.z; a[3]=a0.w;
            a[4]=a1.x; a[5]=a1.y; a[6]=a1.z; a[7]=a1.w;
            float4 b0 = *(const float4*)&Bs[kk][tx * TN];
            bb[0]=b0.x; bb[1]=b0.y; bb[2]=b0.z; bb[3]=b0.w;
#pragma unroll
            for (int i = 0; i < TM; ++i)
#pragma unroll
                for (int j = 0; j < TN; ++j)
                    acc[i][j] = fmaf(a[i], bb[j], acc[i][j]);
        }
        __syncthreads();
    }
#pragma unroll
    for (int i = 0; i < TM; ++i) {
        int row = bm + ty * TM + i;
#pragma unroll
        for (int j = 0; j < TN; ++j) {
            int col = bn + tx * TN + j;
            C[(size_t)row * N + col] = acc[i][j] + bias[col];
        }
    }
}

// ---------------------------------------------------------------------------
// 4. LIF over T
__global__ __launch_bounds__(256) void lif_kernel(const float* src, float* dst, size_t stride) {
    size_t i = ((size_t)blockIdx.x * blockDim.x + threadIdx.x) * 4;
    float v[4] = {0.f, 0.f, 0.f, 0.f};
    for (int t = 0; t < TT; ++t) {
        float4 xv4 = *(const float4*)(src + (size_t)t * stride + i);
        float xv[4] = {xv4.x, xv4.y, xv4.z, xv4.w};
        float sp[4];
#pragma unroll
        for (int j = 0; j < 4; ++j) {
            v[j] = v[j] + (xv[j] - v[j]) * 0.5f;
            bool fire = (v[j] >= 1.0f);
            sp[j] = fire ? 1.0f : 0.0f;
            v[j] = fire ? 0.0f : v[j];
        }
        *(float4*)(dst + (size_t)t * stride + i) = make_float4(sp[0], sp[1], sp[2], sp[3]);
    }
}

// ---------------------------------------------------------------------------
// 4b. pack Q/K spike bits: pk[row][0..7] = q words, pk[row][8..15] = k words
__global__ __launch_bounds__(256) void pack_kernel(const float* __restrict__ spk,
                                                   uint32_t* __restrict__ pk) {
    size_t g = (size_t)blockIdx.x * 256 + threadIdx.x;   // over 16384*512
    int row = (int)(g >> 9);
    int col = (int)(g & 511);
    float v = spk[(size_t)row * C3 + col];
    unsigned long long m = __ballot(v >= 0.5f);
    int lane = threadIdx.x & 63;
    if ((lane & 31) == 0)
        pk[(size_t)row * 16 + (col >> 5)] = (lane < 32) ? (uint32_t)m : (uint32_t)(m >> 32);
}

// ---------------------------------------------------------------------------
// 5. windowed spike attention v3. Block = (t,b,n,hp), 256 threads, q=tid&127 h=tid>>7.
//    Route idx in SGPRs; per-window register base pointers; 2-deep SW pipeline for
//    both V rows (global) and P values (popc+ptab ds_read). FP sequence identical to v2.
__global__ __launch_bounds__(256) void attn_kernel(const float* __restrict__ spk,
                                                   const uint32_t* __restrict__ pk,
                                                   const int* __restrict__ idxws,
                                                   float* __restrict__ out) {
    int bid = blockIdx.x;
    int hp = bid & 3, n = (bid >> 2) & 7, b = (bid >> 5) & 3, t = bid >> 7;
    __shared__ uint32_t kbs[2][512];
    __shared__ float ptab[33][256];
    int tid = threadIdx.x;
    int q = tid & 127, h = tid >> 7;
    int lbase = (t * BB + b) * LL;

    // route indices -> registers (uniform loads; no LDS, no barrier in addr chain)
    const int* ip = idxws + (b * NWIN + n) * TOPKN;
    int s0r = ip[0], s1r = ip[1], s2r = ip[2], s3r = ip[3];

    // stage gathered K bit-words (both halves)
#pragma unroll 4
    for (int e = tid; e < 1024; e += 256) {
        int hh = e >> 9, kk = e & 511;
        int w = kk >> 7;
        int sw = (w == 0) ? s0r : (w == 1) ? s1r : (w == 2) ? s2r : s3r;
        int row = sw * WIN + (kk & 127);
        kbs[hh][kk] = pk[(size_t)(lbase + row) * 16 + 8 + hp * 2 + hh];
    }
    uint32_t qw = pk[(size_t)(lbase + n * WIN + q) * 16 + hp * 2 + h];
    __syncthreads();

    const float ALPHA_SC = 0.17677669529663687f;   // hd^-0.5
    const uint32_t* kbh = kbs[h];
    // pass 1: integer max score
    int smax = 0;
#pragma unroll 8
    for (int k = 0; k < 512; ++k) smax = max(smax, __popc(qw & kbh[k]));
    float am = __fmul_rn((float)smax, ALPHA_SC);
    // pass 2: Z (ascending k, identical expression to reference path)
    float Z = 0.0f;
#pragma unroll 8
    for (int k = 0; k < 512; ++k) {
        int s = __popc(qw & kbh[k]);
        Z += expf(__fsub_rn(__fmul_rn((float)s, ALPHA_SC), am));
    }
    // per-thread P table (33 distinct values); own column only -> no barrier needed
    for (int s = 0; s <= 32; ++s)
        ptab[s][tid] = expf(__fsub_rn(__fmul_rn((float)s, ALPHA_SC), am)) / Z;

    // pass 3: PV with fp32 fma against raw spike floats (bitwise == add-or-skip).
    // k ascending = (w, r) lexicographic, one accumulator chain per d -> exact.
    const float* vbase = spk + (size_t)lbase * C3 + 512 + hp * 64 + h * 32;
    float acc[32];
#pragma unroll
    for (int d = 0; d < 32; ++d) acc[d] = 0.0f;

#pragma unroll
    for (int w = 0; w < 4; ++w) {
        int sw = (w == 0) ? s0r : (w == 1) ? s1r : (w == 2) ? s2r : s3r;
        const float* p = vbase + (size_t)sw * (WIN * C3);
        const uint32_t* kw = kbh + w * 128;

        float4 Av[8], Bv[8];
#pragma unroll
        for (int j = 0; j < 8; ++j) Av[j] = ((const float4*)p)[j];
#pragma unroll
        for (int j = 0; j < 8; ++j) Bv[j] = ((const float4*)(p + C3))[j];
        float Pa = ptab[__popc(qw & kw[0])][tid];
        float Pb = ptab[__popc(qw & kw[1])][tid];

        for (int r = 0; r < 128; r += 2) {
            // row r (buffer A)
            {
                float P = Pa;
#pragma unroll
                for (int j = 0; j < 8; ++j) {
                    acc[4*j+0] = fmaf(P, Av[j].x, acc[4*j+0]);
                    acc[4*j+1] = fmaf(P, Av[j].y, acc[4*j+1]);
                    acc[4*j+2] = fmaf(P, Av[j].z, acc[4*j+2]);
                    acc[4*j+3] = fmaf(P, Av[j].w, acc[4*j+3]);
                }
            }
            // prefetch row r+2 (V + P), wrap-masked (extra reads harmless, in-window)
            {
                const float4* pn = (const float4*)(p + (size_t)((r + 2) & 127) * C3);
#pragma unroll
                for (int j = 0; j < 8; ++j) Av[j] = pn[j];
                Pa = ptab[__popc(qw & kw[(r + 2) & 127])][tid];
            }
            // row r+1 (buffer B)
            {
                float P = Pb;
#pragma unroll
                for (int j = 0; j < 8; ++j) {
                    acc[4*j+0] = fmaf(P, Bv[j].x, acc[4*j+0]);
                    acc[4*j+1] = fmaf(P, Bv[j].y, acc[4*j+1]);
                    acc[4*j+2] = fmaf(P, Bv[j].z, acc[4*j+2]);
                    acc[4*j+3] = fmaf(P, Bv[j].w, acc[4*j+3]);
                }
            }
            // prefetch row r+3 (V + P)
            {
                const float4* pn = (const float4*)(p + (size_t)((r + 3) & 127) * C3);
#pragma unroll
                for (int j = 0; j < 8; ++j) Bv[j] = pn[j];
                Pb = ptab[__popc(qw & kw[(r + 3) & 127])][tid];
            }
        }
    }

    size_t obase = (size_t)(lbase + n * WIN + q) * CC + (hp * 2 + h) * 32;
#pragma unroll
    for (int d = 0; d < 32; ++d) out[obase + d] = acc[d];
}

// ---------------------------------------------------------------------------
extern "C" void kernel_launch(void* const* d_in, const int* in_sizes, int n_in,
                              void* d_out, int out_size, void* d_ws, size_t ws_size,
                              hipStream_t stream) {
    const float* x      = (const float*)d_in[0];
    const float* w_qkv  = (const float*)d_in[1];
    const float* b_qkv  = (const float*)d_in[2];
    const float* w_proj = (const float*)d_in[3];
    const float* b_proj = (const float*)d_in[4];
    float* ws = (float*)d_ws;

    float* qkv      = ws;                 // 12582912 floats [T,B,L,3C] (spikes after LIF)
    float* attn_out = ws + 12582912;      // 4194304 floats [T,B,L,C]
    float* proj     = ws + 16777216;      // 4194304 floats [T,B,L,C]
    uint32_t* pkb   = (uint32_t*)proj;    // 262144 u32: aliases proj (dead before gemm_proj)
    float* region   = ws + 20971520;      // 8192 floats
    int*   idxp     = (int*)(ws + 20979712);  // 128 ints
    float* outp     = (float*)d_out;

    region_kernel<<<dim3(BB * NWIN), dim3(256), 0, stream>>>(x, region);
    route_kernel<<<dim3(BB), dim3(64), 0, stream>>>(region, idxp);
    gemm_bias<<<dim3(128, 12), dim3(256), 0, stream>>>(x, w_qkv, b_qkv, qkv,
                                                       TT * BB * LL, C3, CC);
    lif_kernel<<<dim3(3072), dim3(256), 0, stream>>>(qkv, qkv, (size_t)BB * LL * C3);
    pack_kernel<<<dim3(32768), dim3(256), 0, stream>>>(qkv, pkb);
    attn_kernel<<<dim3(TT * BB * NWIN * 4), dim3(256), 0, stream>>>(qkv, pkb, idxp, attn_out);
    gemm_bias<<<dim3(128, 4), dim3(256), 0, stream>>>(attn_out, w_proj, b_proj, proj,
                                                      TT * BB * LL, CC, CC);
    lif_kernel<<<dim3(1024), dim3(256), 0, stream>>>(proj, outp, (size_t)BB * LL * CC);
}